// Round 8
// baseline (264.214 us; speedup 1.0000x reference)
//
#include <hip/hip_runtime.h>
#include <stdint.h>

typedef __bf16 bf16x8 __attribute__((ext_vector_type(8)));
typedef float  f32x4  __attribute__((ext_vector_type(4)));

__device__ __forceinline__ uint16_t f32_to_bf16_rne(float f) {
    uint32_t u = __float_as_uint(f);
    uint32_t r = (u + 0x7FFFu + ((u >> 16) & 1u)) >> 16;
    return (uint16_t)r;
}

// ---------------------------------------------------------------------------
// Weight pack (bf16 in d_ws), dense blocked-K row-major:
//   [level][kb][n(272 rows, 267 real)][32 k]  (64 B per row per kb-block)
//   level elem offsets: L0=0 (KB=8), L1=69632 (KB=16), L2=208896 (KB=32)
//   total 487424 elems = 975 KB. Fragment for lane (gq,lc), tile nt, step kb:
//   16B at  PKOFF + kb*8704 + (nt*16+lc)*32 + gq*8   -> k = kb*32 + gq*8 + j.
// ---------------------------------------------------------------------------
__global__ void pack_w(const float* __restrict__ w0, const float* __restrict__ w1,
                       const float* __restrict__ w2, uint16_t* __restrict__ pk) {
    int e = blockIdx.x * 256 + threadIdx.x;
    if (e >= 487424) return;
    int C; const float* w; int base;
    if (e < 69632)       { base = 0;      C = 256;  w = w0; }
    else if (e < 208896) { base = 69632;  C = 512;  w = w1; }
    else                 { base = 208896; C = 1024; w = w2; }
    int r  = e - base;
    int kb = r / 8704;  r -= kb * 8704;
    int n  = r >> 5;    int c = r & 31;       // k_local = c
    uint16_t v = 0;
    if (n < 267) v = f32_to_bf16_rne(w[n * C + kb * 32 + c]);
    pk[e] = v;
}

// ---------------------------------------------------------------------------
// Barrier-free, LDS-free fused GEMM+decode. One wave (64 thr) per block.
// Wave owns ONE m-tile (16 hw) x 17 n-tiles (272 n, 267 real).
//   -> acc = 17 x f32x4 = 68 VGPR; total ~130 VGPR; launch_bounds(64,3)
//      caps unified regs at 170 -> NO spill, 3 waves/SIMD for TLP.
// X: zero reuse -> per-lane direct global loads (64B coalesced segments),
//    1-step register prefetch. W: L1/L2-resident packed fragments, dwordx4.
// C/D map (16x16x32): col = lane&15 (hw), row = 4*(lane>>4)+reg (n).
// ---------------------------------------------------------------------------
template<int C, int HW, int NX, int ROWOFF, int PKOFF>
__device__ __forceinline__ void gemm_body(
    const float* __restrict__ x, const float* __restrict__ bias,
    const uint16_t* __restrict__ pk, float* __restrict__ out,
    int m0, float stride_,
    float ax0, float ay0, float ax1, float ay1, float ax2, float ay2)
{
    const int l  = threadIdx.x;     // 0..63
    const int gq = l >> 4;
    const int lc = l & 15;

    // per-lane output position (16-row m-tile never straddles a batch image:
    // HW in {6400,1600,400} are multiples of 16)
    const int ml  = m0 + lc;
    const int bi  = ml / HW;
    const int hwp = ml - bi * HW;

    // X pointer at k = 8*gq (this lane's k-rows are 8*gq + e, e=0..7)
    const float* xp = x + (size_t)bi * C * HW + hwp + (size_t)(8 * gq) * HW;

    const uint16_t* wp = pk + PKOFF + lc * 32 + gq * 8;

    f32x4 acc[17];
    #pragma unroll
    for (int j = 0; j < 17; ++j) acc[j] = (f32x4){0.f, 0.f, 0.f, 0.f};

    // prefetch X for kb=0
    float xf[8];
    #pragma unroll
    for (int e = 0; e < 8; ++e) xf[e] = xp[(size_t)e * HW];

    const int KB = C / 32;
    #pragma unroll 1
    for (int kb = 0; kb < KB; ++kb) {
        // convert current X regs to bf16 frag
        bf16x8 bfr;
        #pragma unroll
        for (int e = 0; e < 8; ++e) bfr[e] = (__bf16)xf[e];
        // issue next-step X loads early (hide HBM latency under W+MFMA chain)
        if (kb + 1 < KB) {
            const float* nx = xp + (size_t)(kb + 1) * 32 * HW;
            #pragma unroll
            for (int e = 0; e < 8; ++e) xf[e] = nx[(size_t)e * HW];
        }
        // W fragments (L1/L2 hit) + MFMA
        const uint16_t* wrow = wp + kb * 8704;
        #pragma unroll
        for (int nt = 0; nt < 17; ++nt) {
            bf16x8 af = *(const bf16x8*)(wrow + nt * 512);
            acc[nt] = __builtin_amdgcn_mfma_f32_16x16x32_bf16(af, bfr, acc[nt], 0, 0, 0);
        }
    }

    // ---- epilogue: decode + scatter store ----
    const int gy = hwp / NX;
    const int gx = hwp - gy * NX;
    const int R0 = bi * 25200 + ROWOFF + hwp;
    const float fgx = (float)gx, fgy = (float)gy;
    #pragma unroll
    for (int nt = 0; nt < 17; ++nt) {
        #pragma unroll
        for (int r = 0; r < 4; ++r) {
            const int n = nt * 16 + 4 * gq + r;
            if (nt == 16 && n >= 267) continue;   // folds away for nt<16
            const int a = (n >= 178) ? 2 : (n >= 89 ? 1 : 0);
            const int o = n - a * 89;
            float v = acc[nt][r] + bias[n];
            float y;
            if (o == 0) {
                y = (__builtin_amdgcn_rcpf(1.0f + __expf(-v)) + fgx) * stride_;
            } else if (o == 1) {
                y = (__builtin_amdgcn_rcpf(1.0f + __expf(-v)) + fgy) * stride_;
            } else if (o == 2) {
                float ax = (a == 0) ? ax0 : (a == 1 ? ax1 : ax2);
                y = __expf(v) * ax;
            } else if (o == 3) {
                float ay = (a == 0) ? ay0 : (a == 1 ? ay1 : ay2);
                y = __expf(v) * ay;
            } else {
                y = __builtin_amdgcn_rcpf(1.0f + __expf(-v));
            }
            out[(size_t)(R0 + a * HW) * 89 + o] = y;
        }
    }
}

__global__ __launch_bounds__(64, 3) void detect_gemm(
    const float* __restrict__ x0, const float* __restrict__ x1, const float* __restrict__ x2,
    const float* __restrict__ b0, const float* __restrict__ b1, const float* __restrict__ b2,
    const uint16_t* __restrict__ pk, float* __restrict__ out)
{
    const int bid = blockIdx.x;
    // longest blocks (level 2, 32 K-steps) first to avoid a serial tail
    if (bid < 200) {
        gemm_body<1024, 400, 20, 24000, 208896>(x2, b2, pk, out, bid * 16, 32.f,
                                                116.f, 90.f, 156.f, 198.f, 373.f, 326.f);
    } else if (bid < 1000) {
        gemm_body<512, 1600, 40, 19200, 69632>(x1, b1, pk, out, (bid - 200) * 16, 16.f,
                                               30.f, 61.f, 62.f, 45.f, 59.f, 119.f);
    } else {
        gemm_body<256, 6400, 80, 0, 0>(x0, b0, pk, out, (bid - 1000) * 16, 8.f,
                                       10.f, 13.f, 16.f, 30.f, 33.f, 23.f);
    }
}

extern "C" void kernel_launch(void* const* d_in, const int* in_sizes, int n_in,
                              void* d_out, int out_size, void* d_ws, size_t ws_size,
                              hipStream_t stream) {
    (void)in_sizes; (void)n_in; (void)out_size; (void)ws_size;
    const float* x0 = (const float*)d_in[0];
    const float* w0 = (const float*)d_in[1];
    const float* b0 = (const float*)d_in[2];
    const float* x1 = (const float*)d_in[3];
    const float* w1 = (const float*)d_in[4];
    const float* b1 = (const float*)d_in[5];
    const float* x2 = (const float*)d_in[6];
    const float* w2 = (const float*)d_in[7];
    const float* b2 = (const float*)d_in[8];
    uint16_t* pk = (uint16_t*)d_ws;   // 974,848 B used
    float* out = (float*)d_out;

    pack_w<<<1904, 256, 0, stream>>>(w0, w1, w2, pk);
    detect_gemm<<<4200, 64, 0, stream>>>(x0, x1, x2, b0, b1, b2, pk, out);
}

// Round 12
// 206.563 us; speedup vs baseline: 1.2791x; 1.2791x over previous
//
#include <hip/hip_runtime.h>
#include <stdint.h>

typedef __bf16 bf16x8 __attribute__((ext_vector_type(8)));
typedef float  f32x4  __attribute__((ext_vector_type(4)));

__device__ __forceinline__ uint16_t f32_to_bf16_rne(float f) {
    uint32_t u = __float_as_uint(f);
    uint32_t r = (u + 0x7FFFu + ((u >> 16) & 1u)) >> 16;
    return (uint16_t)r;
}

// ---------------------------------------------------------------------------
// Weight pack layout (bf16 ushorts in d_ws):
//   level offsets (elements): L0=0, L1=87040, L2=261120, total 609280 (1.22MB)
//   per 32-k block: 272 rows (n, padded from 267) x 40 elems (4 data chunks of
//   8 k + 1 pad chunk) = 10880 elems = 21760 B = 1360 uint4.  chunk g holds
//   k = 32*kb + 8g+j.  80B row pitch -> conflict-free ds_read_b128 A-frags.
// ---------------------------------------------------------------------------
__global__ void pack_w(const float* __restrict__ w0, const float* __restrict__ w1,
                       const float* __restrict__ w2, uint16_t* __restrict__ pk) {
    int e = blockIdx.x * 256 + threadIdx.x;
    if (e >= 609280) return;
    int C; const float* w; int base;
    if (e < 87040)       { base = 0;      C = 256;  w = w0; }
    else if (e < 261120) { base = 87040;  C = 512;  w = w1; }
    else                 { base = 261120; C = 1024; w = w2; }
    int r   = e - base;
    int kb  = r / 10880; r -= kb * 10880;
    int n   = r / 40;    int c = r - n * 40;
    int g = c >> 3, j = c & 7;
    uint16_t v = 0;
    if (g < 4 && n < 267) {
        int k = kb * 32 + g * 8 + j;
        v = f32_to_bf16_rne(w[n * C + k]);
    }
    pk[e] = v;
}

// ---------------------------------------------------------------------------
// Fused GEMM + decode. Block: 512 thr = 8 waves, BM=128. Wave w owns m-tile w
// (16 hw rows) x 17 n-tiles -> acc[17] = 68 regs/wave.
// W-block per K-step = 10880 uint16 = 1360 uint4 (FIXED: was 680 => half of
// Wlds was stale LDS -> NaN in R9, k-shifted reads in R2).
// A operand = W (rows = out-channel n), B operand = X (cols = hw).
// C/D (16x16x32): col = lane&15 (hw), row = 4*(lane>>4)+reg (n).  [verified]
// ---------------------------------------------------------------------------
template<int C, int HW, int NX, int ROWOFF, int PKOFF>
__device__ __forceinline__ void gemm_body(
    const float* __restrict__ x, const float* __restrict__ bias,
    const uint16_t* __restrict__ pk, float* __restrict__ out,
    int m0, float stride_,
    float ax0, float ay0, float ax1, float ay1, float ax2, float ay2)
{
    constexpr int WBLK_U4 = (10880 * (int)sizeof(uint16_t)) / (int)sizeof(uint4); // 1360

    __shared__ alignas(16) uint16_t Wlds[10880];   // 21760 B
    __shared__ alignas(16) uint16_t Xlds[4096];    // 8192 B, [k][128hw] 32B-unit swizzled

    const int t  = threadIdx.x;
    const int w  = t >> 6;          // 0..7
    const int l  = t & 63;
    const int gq = l >> 4;
    const int lc = l & 15;

    // --- staging-X per-thread precompute: this thread stages hw pair (hw0, hw0+1)
    const int hw0  = 2 * l;                 // block-local m offset, even, < 128
    const int m_s  = m0 + hw0;
    const int b_s  = m_s / HW;              // HW compile-time -> magic mul
    const int hwp_s = m_s - b_s * HW;       // pair never straddles batch (HW even)
    const float* xp = x + (size_t)b_s * C * HW + hwp_s + (size_t)w * HW;

    const uint4* pks = (const uint4*)(pk + PKOFF);

    f32x4 acc[17];
    #pragma unroll
    for (int j = 0; j < 17; ++j) acc[j] = (f32x4){0.f, 0.f, 0.f, 0.f};

    const int KB = C / 32;
    for (int kb = 0; kb < KB; ++kb) {
        if (kb) __syncthreads();            // WAR guard vs previous compute

        // stage W: 1360 uint4 = full 21760B block (coalesced, conflict-free)
        {
            const uint4* wsrc = pks + (size_t)kb * WBLK_U4;
            uint4* wdst = (uint4*)Wlds;
            wdst[t]       = wsrc[t];
            wdst[512 + t] = wsrc[512 + t];
            if (t < WBLK_U4 - 1024) wdst[1024 + t] = wsrc[1024 + t];
        }
        // stage X: wave w covers k_local = 8i+w, i=0..3; 64 lanes x float2 = 128 hw
        #pragma unroll
        for (int i = 0; i < 4; ++i) {
            const int kl = 8 * i + w;
            float2 f = *(const float2*)(xp + (size_t)(8 * i) * HW);
            uint32_t p = ((uint32_t)f32_to_bf16_rne(f.y) << 16) | f32_to_bf16_rne(f.x);
            // 32B-unit XOR swizzle: unit u = hw>>4, u' = u ^ (k>>3)
            int off = kl * 128 + 16 * ((hw0 >> 4) ^ (kl >> 3)) + (hw0 & 15);
            *(uint32_t*)&Xlds[off] = p;
        }
        __syncthreads();

        // B frag: per-lane k-gather, k = 8*gq + e (same bijection as W pack)
        bf16x8 bfr;
        {
            union { uint16_t s[8]; bf16x8 v; } bb;
            #pragma unroll
            for (int e = 0; e < 8; ++e) {
                int kl = 8 * gq + e;
                bb.s[e] = Xlds[kl * 128 + 16 * (w ^ gq) + lc];
            }
            bfr = bb.v;
        }
        #pragma unroll
        for (int nt = 0; nt < 17; ++nt) {
            bf16x8 af = *(const bf16x8*)&Wlds[(nt * 16 + lc) * 40 + gq * 8];
            acc[nt] = __builtin_amdgcn_mfma_f32_16x16x32_bf16(af, bfr, acc[nt], 0, 0, 0);
        }
        xp += (size_t)32 * HW;
    }

    // ---- epilogue: decode + scatter store ----
    const int mlane = m0 + w * 16 + lc;
    const int bb  = mlane / HW;
    const int hwp = mlane - bb * HW;
    const int gy  = hwp / NX;
    const int gx  = hwp - gy * NX;
    const int R0  = bb * 25200 + ROWOFF + hwp;
    const float fgx = (float)gx, fgy = (float)gy;
    #pragma unroll
    for (int nt = 0; nt < 17; ++nt) {
        #pragma unroll
        for (int r = 0; r < 4; ++r) {
            const int n = nt * 16 + 4 * gq + r;
            if (nt == 16 && n >= 267) continue;   // folds away for nt<16
            const int a = (n >= 178) ? 2 : (n >= 89 ? 1 : 0);
            const int o = n - a * 89;
            float v = acc[nt][r] + bias[n];
            float y;
            if (o == 0) {
                y = (__builtin_amdgcn_rcpf(1.0f + __expf(-v)) + fgx) * stride_;
            } else if (o == 1) {
                y = (__builtin_amdgcn_rcpf(1.0f + __expf(-v)) + fgy) * stride_;
            } else if (o == 2) {
                float ax = (a == 0) ? ax0 : (a == 1 ? ax1 : ax2);
                y = __expf(v) * ax;
            } else if (o == 3) {
                float ay = (a == 0) ? ay0 : (a == 1 ? ay1 : ay2);
                y = __expf(v) * ay;
            } else {
                y = __builtin_amdgcn_rcpf(1.0f + __expf(-v));
            }
            out[(size_t)(R0 + a * HW) * 89 + o] = y;
        }
    }
}

__global__ __launch_bounds__(512, 4) void detect_gemm(
    const float* __restrict__ x0, const float* __restrict__ x1, const float* __restrict__ x2,
    const float* __restrict__ b0, const float* __restrict__ b1, const float* __restrict__ b2,
    const uint16_t* __restrict__ pk, float* __restrict__ out)
{
    const int bid = blockIdx.x;
    // longest blocks (level 2, 32 K-steps) first to avoid a serial tail
    if (bid < 25) {
        gemm_body<1024, 400, 20, 24000, 261120>(x2, b2, pk, out, bid * 128, 32.f,
                                                116.f, 90.f, 156.f, 198.f, 373.f, 326.f);
    } else if (bid < 125) {
        gemm_body<512, 1600, 40, 19200, 87040>(x1, b1, pk, out, (bid - 25) * 128, 16.f,
                                               30.f, 61.f, 62.f, 45.f, 59.f, 119.f);
    } else {
        gemm_body<256, 6400, 80, 0, 0>(x0, b0, pk, out, (bid - 125) * 128, 8.f,
                                       10.f, 13.f, 16.f, 30.f, 33.f, 23.f);
    }
}

extern "C" void kernel_launch(void* const* d_in, const int* in_sizes, int n_in,
                              void* d_out, int out_size, void* d_ws, size_t ws_size,
                              hipStream_t stream) {
    (void)in_sizes; (void)n_in; (void)out_size; (void)ws_size;
    const float* x0 = (const float*)d_in[0];
    const float* w0 = (const float*)d_in[1];
    const float* b0 = (const float*)d_in[2];
    const float* x1 = (const float*)d_in[3];
    const float* w1 = (const float*)d_in[4];
    const float* b1 = (const float*)d_in[5];
    const float* x2 = (const float*)d_in[6];
    const float* w2 = (const float*)d_in[7];
    const float* b2 = (const float*)d_in[8];
    uint16_t* pk = (uint16_t*)d_ws;   // 1,218,560 B used
    float* out = (float*)d_out;

    pack_w<<<2380, 256, 0, stream>>>(w0, w1, w2, pk);
    detect_gemm<<<525, 512, 0, stream>>>(x0, x1, x2, b0, b1, b2, pk, out);
}